// Round 5
// baseline (515.949 us; speedup 1.0000x reference)
//
#include <hip/hip_runtime.h>

#define NN 100000
#define NE 1600000
#define C 32

#define SHIFT 8
#define BINW 256                              // nodes per bin
#define NBIN ((NN + BINW - 1) / BINW)         // 391
#define CAP 5120                              // per-bin segment capacity (16 sigma)
#define EPB 2048                              // edges per block (binning)
#define NBLK ((NE + EPB - 1) / EPB)           // 782

__device__ __forceinline__ unsigned bf16rne(float f) {
    unsigned u = __float_as_uint(f);
    return (u + 0x7fffu + ((u >> 16) & 1u)) >> 16;
}
__device__ __forceinline__ float blo(unsigned u) { return __uint_as_float(u << 16); }
__device__ __forceinline__ float bhi(unsigned u) { return __uint_as_float(u & 0xffff0000u); }

// native LDS float atomic (fire-and-forget; default codegen CAS-expands
// __shared__ float atomicAdd, which was round-1's 346us disaster).
// Generic pointers to LDS carry the LDS byte offset in their low 32 bits.
// NOTE: these are invisible to the compiler's waitcnt pass — the caller
// MUST drain lgkmcnt manually before any barrier/read of the accumulator.
__device__ __forceinline__ void ds_add4(float* p, float v0, float v1,
                                        float v2, float v3) {
    unsigned a = (unsigned)(unsigned long long)p;
    asm volatile("ds_add_f32 %0, %1" : : "v"(a), "v"(v0) : "memory");
    asm volatile("ds_add_f32 %0, %1 offset:4" : : "v"(a), "v"(v1) : "memory");
    asm volatile("ds_add_f32 %0, %1 offset:8" : : "v"(a), "v"(v2) : "memory");
    asm volatile("ds_add_f32 %0, %1 offset:12" : : "v"(a), "v"(v3) : "memory");
}

// ---------------- kernels ----------------

// zero per-bin cursors + per-node degree (ws is poisoned each iter)
__global__ __launch_bounds__(256) void k_init(int* __restrict__ gcur,
                                              int* __restrict__ deg) {
    int i = blockIdx.x * 256 + threadIdx.x;
    if (i < NBIN) gcur[i] = i * CAP;
    for (int j = i; j < NN; j += gridDim.x * 256) deg[j] = 0;
}

// LDS hist of window (+ global per-node degree atomics) -> claim bases via
// one global atomic per (block,bin) -> scatter with LDS cursors.
__global__ __launch_bounds__(256) void k_bin(const int* __restrict__ ei,
                                             int* __restrict__ gcur,
                                             int* __restrict__ deg,
                                             int* __restrict__ tmp) {
    __shared__ int lh[NBIN];                  // counts, then cursors
    int b = blockIdx.x, t = threadIdx.x;
    for (int i = t; i < NBIN; i += 256) lh[i] = 0;
    __syncthreads();
    int e0 = b * EPB, e1 = min(e0 + EPB, NE); // windows %4 == 0
    const int4* src4 = (const int4*)ei;
    const int4* col4 = (const int4*)(ei + NE);
    for (int q = (e0 >> 2) + t; q < (e1 >> 2); q += 256) {
        int4 c = col4[q];
        atomicAdd(&lh[c.x >> SHIFT], 1);
        atomicAdd(&lh[c.y >> SHIFT], 1);
        atomicAdd(&lh[c.z >> SHIFT], 1);
        atomicAdd(&lh[c.w >> SHIFT], 1);
        atomicAdd(&deg[c.x], 1);              // L2 atomics, 400KB array
        atomicAdd(&deg[c.y], 1);
        atomicAdd(&deg[c.z], 1);
        atomicAdd(&deg[c.w], 1);
    }
    __syncthreads();
    for (int i = t; i < NBIN; i += 256) {
        int c = lh[i];
        if (c) lh[i] = atomicAdd(&gcur[i], c);   // claim contiguous base
    }
    __syncthreads();
    for (int q = (e0 >> 2) + t; q < (e1 >> 2); q += 256) {   // window L2-hot
        int4 s = src4[q];
        int4 c = col4[q];
        int p0 = atomicAdd(&lh[c.x >> SHIFT], 1);
        tmp[p0] = (s.x << SHIFT) | (c.x & (BINW - 1));
        int p1 = atomicAdd(&lh[c.y >> SHIFT], 1);
        tmp[p1] = (s.y << SHIFT) | (c.y & (BINW - 1));
        int p2 = atomicAdd(&lh[c.z >> SHIFT], 1);
        tmp[p2] = (s.z << SHIFT) | (c.z & (BINW - 1));
        int p3 = atomicAdd(&lh[c.w >> SHIFT], 1);
        tmp[p3] = (s.w << SHIFT) | (c.w & (BINW - 1));
    }
}

// h' = bf16( dinv * (x @ W^T) ), packed 2 channels/uint -> 64B rows.
__global__ __launch_bounds__(256) void k_linear(const float* __restrict__ x,
                                                const float* __restrict__ W,
                                                const int* __restrict__ deg,
                                                unsigned* __restrict__ hu) {
    __shared__ float Ws[C][C + 1];
    __shared__ float xs[16][C];
    int t = threadIdx.x;
    for (int i = t; i < C * C; i += 256)
        Ws[i / C][i % C] = W[i];

    int node0 = blockIdx.x * 16;
#pragma unroll
    for (int i = t; i < 16 * C; i += 256) {
        int idx = node0 * C + i;     // coalesced load of 16 rows
        xs[i >> 5][i & 31] = (idx < NN * C) ? x[idx] : 0.0f;
    }
    __syncthreads();
    int lnode = t >> 4, m = t & 15;
    int node = node0 + lnode;
    if (node < NN) {
        float a0 = 0.0f, a1 = 0.0f;
#pragma unroll
        for (int k = 0; k < C; ++k) {
            float xv = xs[lnode][k];
            a0 += xv * Ws[2 * m][k];
            a1 += xv * Ws[2 * m + 1][k];
        }
        float d = rsqrtf(1.0f + (float)deg[node]);   // deg incl. self-loop
        hu[node * 16 + m] = bf16rne(a0 * d) | (bf16rne(a1 * d) << 16);
    }
}

// fused aggregation: one block per bin streams the bin's unsorted segment,
// gathers hu rows (8 lanes x uint2 = 64B) and ds_add_f32's straight into
// an LDS accumulator. No srt, no off, no per-node wave reduction.
#define AGG_T 512
__global__ __launch_bounds__(AGG_T) void k_aggF(const int* __restrict__ gcur,
                                                const int* __restrict__ tmp,
                                                const uint2* __restrict__ hu2,
                                                const int* __restrict__ deg,
                                                const float* __restrict__ b,
                                                float* __restrict__ out) {
    __shared__ float acc[BINW][33];            // odd stride: spread ds banks
    int bin = blockIdx.x, t = threadIdx.x;
    for (int i = t; i < BINW * 33; i += AGG_T) ((float*)acc)[i] = 0.0f;
    __syncthreads();
    int s0 = bin * CAP;
    int s1 = gcur[bin];                        // s0 + bin count
    int g = t >> 3, m = t & 7;                 // 64 edge-groups x 8 lanes
    int c0 = 4 * m;                            // channels 4m..4m+3
    int e = s0 + g;
    for (; e + 192 < s1; e += 256) {           // 4-deep: 8 loads in flight
        int v0 = tmp[e], v1 = tmp[e + 64], v2 = tmp[e + 128], v3 = tmp[e + 192];
        uint2 u0 = hu2[(v0 >> SHIFT) * 8 + m];
        uint2 u1 = hu2[(v1 >> SHIFT) * 8 + m];
        uint2 u2 = hu2[(v2 >> SHIFT) * 8 + m];
        uint2 u3 = hu2[(v3 >> SHIFT) * 8 + m];
        ds_add4(&acc[v0 & (BINW - 1)][c0], blo(u0.x), bhi(u0.x), blo(u0.y), bhi(u0.y));
        ds_add4(&acc[v1 & (BINW - 1)][c0], blo(u1.x), bhi(u1.x), blo(u1.y), bhi(u1.y));
        ds_add4(&acc[v2 & (BINW - 1)][c0], blo(u2.x), bhi(u2.x), blo(u2.y), bhi(u2.y));
        ds_add4(&acc[v3 & (BINW - 1)][c0], blo(u3.x), bhi(u3.x), blo(u3.y), bhi(u3.y));
    }
    for (; e < s1; e += 64) {
        int v = tmp[e];
        uint2 u = hu2[(v >> SHIFT) * 8 + m];
        ds_add4(&acc[v & (BINW - 1)][c0], blo(u.x), bhi(u.x), blo(u.y), bhi(u.y));
    }
    // CRITICAL: inline-asm DS ops are invisible to the compiler's waitcnt
    // pass — __syncthreads() alone will NOT drain them (round-4 failure:
    // absmax 0.246 from adds still in flight when epilogue read acc).
    asm volatile("s_waitcnt lgkmcnt(0)" ::: "memory");
    __builtin_amdgcn_sched_barrier(0);
    __syncthreads();
    // epilogue: out float4 index == bin*2048 + idx -> fully coalesced
    for (int idx = t; idx < BINW * 8; idx += AGG_T) {
        int loc = idx >> 3, k = idx & 7;
        int node = (bin << SHIFT) + loc;
        if (node >= NN) continue;
        float dn = rsqrtf(1.0f + (float)deg[node]);
        uint2 us = hu2[node * 8 + k];          // self-loop row (pre-scaled)
        float4 bb = ((const float4*)b)[k];
        float o0 = bb.x + dn * (acc[loc][4 * k + 0] + blo(us.x));
        float o1 = bb.y + dn * (acc[loc][4 * k + 1] + bhi(us.x));
        float o2 = bb.z + dn * (acc[loc][4 * k + 2] + blo(us.y));
        float o3 = bb.w + dn * (acc[loc][4 * k + 3] + bhi(us.y));
        ((float4*)out)[node * 8 + k] = make_float4(o0, o1, o2, o3);
    }
}

// ---------------- launch ----------------

extern "C" void kernel_launch(void* const* d_in, const int* in_sizes, int n_in,
                              void* d_out, int out_size, void* d_ws, size_t ws_size,
                              hipStream_t stream) {
    const float* x  = (const float*)d_in[0];
    const int*   ei = (const int*)d_in[1];
    const float* W  = (const float*)d_in[2];
    const float* b  = (const float*)d_in[3];
    float* out = (float*)d_out;

    // ws (~15 MB of 256 MB pool) — no overlays, all buffers distinct
    char* ws = (char*)d_ws;
    size_t o = 0;
    int*      tmp  = (int*)(ws + o);      o += (size_t)NBIN * CAP * 4;    o = (o + 255) & ~(size_t)255;
    unsigned* hu   = (unsigned*)(ws + o); o += (size_t)NN * 16 * 4;       o = (o + 255) & ~(size_t)255;
    int*      gcur = (int*)(ws + o);      o += (size_t)NBIN * 4;          o = (o + 255) & ~(size_t)255;
    int*      deg  = (int*)(ws + o);

    k_init<<<128, 256, 0, stream>>>(gcur, deg);
    k_bin<<<NBLK, 256, 0, stream>>>(ei, gcur, deg, tmp);
    k_linear<<<(NN + 15) / 16, 256, 0, stream>>>(x, W, deg, hu);
    k_aggF<<<NBIN, AGG_T, 0, stream>>>(gcur, tmp, (const uint2*)hu, deg, b, out);
}

// Round 6
// 161.593 us; speedup vs baseline: 3.1929x; 3.1929x over previous
//
#include <hip/hip_runtime.h>

#define NN 100000
#define NE 1600000
#define C 32

#define SHIFT 8
#define BINW 256                              // nodes per bin
#define NBIN ((NN + BINW - 1) / BINW)         // 391
#define EPB 8192                              // edges per block (binning)
#define NCHK ((NE + EPB - 1) / EPB)           // 196 chunks = k_bin blocks
#define SLACK 56                              // slots per (chunk,bin); lambda~21, max~43
#define CAPT (NCHK * SLACK)                   // 10976 tmp slots per bin
#define SCAP 5120                             // compact srt capacity per bin (4096+16sigma)

__device__ __forceinline__ unsigned bf16rne(float f) {
    unsigned u = __float_as_uint(f);
    return (u + 0x7fffu + ((u >> 16) & 1u)) >> 16;
}
__device__ __forceinline__ float blo(unsigned u) { return __uint_as_float(u << 16); }
__device__ __forceinline__ float bhi(unsigned u) { return __uint_as_float(u & 0xffff0000u); }

// ---------------- kernels ----------------

// single-pass scatter into chunk-partitioned bins. Block b statically owns
// slots [bin*CAPT + b*SLACK, +SLACK) of every bin: no histogram pass, no
// scan kernels, no global claim atomics (round-3's gcur hot-line serializer).
__global__ __launch_bounds__(256) void k_bin(const int* __restrict__ ei,
                                             int* __restrict__ tmp,
                                             int* __restrict__ cfill) {
    __shared__ int lcur[NBIN];
    int b = blockIdx.x, t = threadIdx.x;
    for (int i = t; i < NBIN; i += 256) lcur[i] = i * CAPT + b * SLACK;
    __syncthreads();
    int e0 = b * EPB, e1 = min(e0 + EPB, NE);   // windows %4 == 0
    const int4* src4 = (const int4*)ei;
    const int4* col4 = (const int4*)(ei + NE);
    for (int q = (e0 >> 2) + t; q < (e1 >> 2); q += 256) {
        int4 s = src4[q];
        int4 c = col4[q];
        int p0 = atomicAdd(&lcur[c.x >> SHIFT], 1);
        tmp[p0] = (s.x << SHIFT) | (c.x & (BINW - 1));
        int p1 = atomicAdd(&lcur[c.y >> SHIFT], 1);
        tmp[p1] = (s.y << SHIFT) | (c.y & (BINW - 1));
        int p2 = atomicAdd(&lcur[c.z >> SHIFT], 1);
        tmp[p2] = (s.z << SHIFT) | (c.z & (BINW - 1));
        int p3 = atomicAdd(&lcur[c.w >> SHIFT], 1);
        tmp[p3] = (s.w << SHIFT) | (c.w & (BINW - 1));
    }
    __syncthreads();
    for (int i = t; i < NBIN; i += 256)                       // chunk fills
        cfill[i * NCHK + b] = lcur[i] - (i * CAPT + b * SLACK);
}

// one block per bin: walk the gapped segment (validity from chunk fills),
// count+stash -> wave scan -> place into compact gapped srt.
// off[node] packs {local_start (16b) | deg (16b)}.
__global__ __launch_bounds__(256) void k_placeB(const int* __restrict__ cfill,
                                                const int* __restrict__ tmp,
                                                int* __restrict__ srt,
                                                int* __restrict__ off,
                                                float* __restrict__ dinv) {
    __shared__ int ccnt[NCHK];
    __shared__ int lcnt[BINW];
    __shared__ int lcur[BINW];
    __shared__ int stash[CAPT];                // 43KB; <64KB static limit
    __shared__ int wtot[4], wbase[4];
    int bin = blockIdx.x, t = threadIdx.x;
    int w = t >> 6, lane = t & 63;
    if (t < NCHK) ccnt[t] = cfill[bin * NCHK + t];
    lcnt[t] = 0;
    __syncthreads();
    int base = bin * CAPT;
    for (int s = t; s < CAPT; s += 256) {
        int chunk = s / SLACK;                 // magic-mul division
        int o = s - chunk * SLACK;
        if (o < ccnt[chunk]) {
            int v = tmp[base + s];
            stash[s] = v;
            atomicAdd(&lcnt[v & (BINW - 1)], 1);
        }
    }
    __syncthreads();
    int cv = lcnt[t];
    int v = cv;                                // inclusive scan within wave
#pragma unroll
    for (int d = 1; d < 64; d <<= 1) {
        int u = __shfl_up(v, d);
        if (lane >= d) v += u;
    }
    if (lane == 63) wtot[w] = v;
    __syncthreads();
    if (t == 0) {
        int r = 0;
#pragma unroll
        for (int k = 0; k < 4; ++k) { wbase[k] = r; r += wtot[k]; }
    }
    __syncthreads();
    int loc = wbase[w] + v - cv;               // exclusive local offset in bin
    lcur[t] = bin * SCAP + loc;
    int node = (bin << SHIFT) + t;
    if (node < NN) {
        off[node] = loc | (cv << 16);
        dinv[node] = rsqrtf(1.0f + (float)cv); // deg incl. self-loop
    }
    __syncthreads();
    for (int s = t; s < CAPT; s += 256) {
        int chunk = s / SLACK;
        int o = s - chunk * SLACK;
        if (o < ccnt[chunk]) {
            int e = stash[s];
            int pos = atomicAdd(&lcur[e & (BINW - 1)], 1);
            srt[pos] = e >> SHIFT;
        }
    }
}

// h' = bf16( dinv * (x @ W^T) ), packed 2 channels/uint -> 64B rows.
__global__ __launch_bounds__(256) void k_linear(const float* __restrict__ x,
                                                const float* __restrict__ W,
                                                const float* __restrict__ dinv,
                                                unsigned* __restrict__ hu) {
    __shared__ float Ws[C][C + 1];
    __shared__ float xs[16][C];
    int t = threadIdx.x;
    for (int i = t; i < C * C; i += 256)
        Ws[i / C][i % C] = W[i];

    int node0 = blockIdx.x * 16;
#pragma unroll
    for (int i = t; i < 16 * C; i += 256) {
        int idx = node0 * C + i;     // coalesced load of 16 rows
        xs[i >> 5][i & 31] = (idx < NN * C) ? x[idx] : 0.0f;
    }
    __syncthreads();
    int lnode = t >> 4, m = t & 15;
    int node = node0 + lnode;
    if (node < NN) {
        float a0 = 0.0f, a1 = 0.0f;
#pragma unroll
        for (int k = 0; k < C; ++k) {
            float xv = xs[lnode][k];
            a0 += xv * Ws[2 * m][k];
            a1 += xv * Ws[2 * m + 1][k];
        }
        float d = dinv[node];
        hu[node * 16 + m] = bf16rne(a0 * d) | (bf16rne(a1 * d) << 16);
    }
}

// one 64-lane wave per node; 8 slots x 8 lanes, uint2 (8B) per lane ->
// 8 edge rows in flight per load instr, 32 in the unrolled body.
__global__ __launch_bounds__(256) void k_agg(const int* __restrict__ off,
                                             const int* __restrict__ srt,
                                             const uint2* __restrict__ hu2,
                                             const float* __restrict__ dinv,
                                             const float* __restrict__ b,
                                             float* __restrict__ out) {
    int n = (blockIdx.x * blockDim.x + threadIdx.x) >> 6;
    if (n >= NN) return;
    int lane = threadIdx.x & 63;
    int q = lane >> 3, m = lane & 7;     // slot q, lane m -> channels 4m..4m+3
    int ov = off[n];
    int beg = (n >> SHIFT) * SCAP + (ov & 0xffff);
    int end = beg + (ov >> 16);
    float s0 = 0.0f, s1 = 0.0f, s2 = 0.0f, s3 = 0.0f;
    int j = beg + q;
    for (; j + 24 < end; j += 32) {
        int r0 = srt[j], r1 = srt[j + 8], r2 = srt[j + 16], r3 = srt[j + 24];
        uint2 u0 = hu2[r0 * 8 + m];
        uint2 u1 = hu2[r1 * 8 + m];
        uint2 u2 = hu2[r2 * 8 + m];
        uint2 u3 = hu2[r3 * 8 + m];
        s0 += blo(u0.x); s1 += bhi(u0.x); s2 += blo(u0.y); s3 += bhi(u0.y);
        s0 += blo(u1.x); s1 += bhi(u1.x); s2 += blo(u1.y); s3 += bhi(u1.y);
        s0 += blo(u2.x); s1 += bhi(u2.x); s2 += blo(u2.y); s3 += bhi(u2.y);
        s0 += blo(u3.x); s1 += bhi(u3.x); s2 += blo(u3.y); s3 += bhi(u3.y);
    }
    for (; j < end; j += 8) {
        uint2 u = hu2[srt[j] * 8 + m];
        s0 += blo(u.x); s1 += bhi(u.x); s2 += blo(u.y); s3 += bhi(u.y);
    }
#pragma unroll
    for (int d = 8; d < 64; d <<= 1) {
        s0 += __shfl_xor(s0, d);
        s1 += __shfl_xor(s1, d);
        s2 += __shfl_xor(s2, d);
        s3 += __shfl_xor(s3, d);
    }
    if (q == 0) {
        float dn = dinv[n];
        uint2 us = hu2[n * 8 + m];       // self-loop row (pre-scaled)
        float4 bb = ((const float4*)b)[m];
        float o0 = bb.x + dn * (s0 + blo(us.x));
        float o1 = bb.y + dn * (s1 + bhi(us.x));
        float o2 = bb.z + dn * (s2 + blo(us.y));
        float o3 = bb.w + dn * (s3 + bhi(us.y));
        ((float4*)out)[n * 8 + m] = make_float4(o0, o1, o2, o3);
    }
}

// ---------------- launch ----------------

extern "C" void kernel_launch(void* const* d_in, const int* in_sizes, int n_in,
                              void* d_out, int out_size, void* d_ws, size_t ws_size,
                              hipStream_t stream) {
    const float* x  = (const float*)d_in[0];
    const int*   ei = (const int*)d_in[1];
    const float* W  = (const float*)d_in[2];
    const float* b  = (const float*)d_in[3];
    float* out = (float*)d_out;

    // ws (~33 MB of 256 MB pool) — no overlays, all buffers distinct
    char* ws = (char*)d_ws;
    size_t o = 0;
    int*      tmp   = (int*)(ws + o);      o += (size_t)NBIN * CAPT * 4;   o = (o + 255) & ~(size_t)255;
    int*      srt   = (int*)(ws + o);      o += (size_t)NBIN * SCAP * 4;   o = (o + 255) & ~(size_t)255;
    unsigned* hu    = (unsigned*)(ws + o); o += (size_t)NN * 16 * 4;       o = (o + 255) & ~(size_t)255;
    int*      cfill = (int*)(ws + o);      o += (size_t)NBIN * NCHK * 4;   o = (o + 255) & ~(size_t)255;
    int*      off   = (int*)(ws + o);      o += (size_t)NN * 4;            o = (o + 255) & ~(size_t)255;
    float*    dinv  = (float*)(ws + o);

    k_bin<<<NCHK, 256, 0, stream>>>(ei, tmp, cfill);
    k_placeB<<<NBIN, 256, 0, stream>>>(cfill, tmp, srt, off, dinv);
    k_linear<<<(NN + 15) / 16, 256, 0, stream>>>(x, W, dinv, hu);
    k_agg<<<(NN * 64 + 255) / 256, 256, 0, stream>>>(off, srt, (const uint2*)hu, dinv, b, out);
}